// Round 8
// baseline (676.232 us; speedup 1.0000x reference)
//
#include <hip/hip_runtime.h>

#define NB 4
#define NN 256
#define NH 128
#define LN_EPS 1e-5f

__device__ __forceinline__ float elu1(float x){
  return x > 0.f ? x : (__expf(x) - 1.f);
}

// K0: lin_in[b,i,:] = v@W_in.T + b_in ; lin_out[b,i,:] = v@W_out.T + b_out (fp32 exact)
__global__ __launch_bounds__(128) void lin_vw_kernel(
    const float* __restrict__ v,
    const float* __restrict__ W_in, const float* __restrict__ b_in,
    const float* __restrict__ W_out, const float* __restrict__ b_out,
    float* __restrict__ lin_in, float* __restrict__ lin_out)
{
  const int row = blockIdx.x;    // b*NN + i
  const int t = threadIdx.x;     // output col
  __shared__ float vs[NH];
  vs[t] = v[(size_t)row*NH + t];
  __syncthreads();
  const float4* wi = (const float4*)(W_in + t*NH);
  const float4* wo = (const float4*)(W_out + t*NH);
  const float4* vv = (const float4*)vs;
  float ai = b_in[t], ao = b_out[t];
  #pragma unroll
  for (int k = 0; k < NH/4; ++k){
    float4 x = vv[k];
    float4 a = wi[k], bq = wo[k];
    ai += x.x*a.x + x.y*a.y + x.z*a.z + x.w*a.w;
    ao += x.x*bq.x + x.y*bq.y + x.z*bq.z + x.w*bq.w;
  }
  lin_in[(size_t)row*NH + t]  = ai;
  lin_out[(size_t)row*NH + t] = ao;
}

// A': pure fp32 VALU: lin_e = e@W_e2e.T + lin_in + lin_out + b_e2e
//     -> LN -> ELU -> diag/e_mask zero -> out_e.  Same logic as the MFMA
//     version, GEMM bisected out.
__global__ __launch_bounds__(256) void nri_eout_fp32_kernel(
    const float* __restrict__ e,
    const int* __restrict__ e_mask,
    const float* __restrict__ W_e2e, const float* __restrict__ b_e2e,
    const float* __restrict__ g_e,   const float* __restrict__ be_e,
    const float* __restrict__ lin_in, const float* __restrict__ lin_out,
    float* __restrict__ out_e)
{
  const int blk = blockIdx.x, b = blk >> 8, j = blk & (NN-1);
  const int tid = threadIdx.x, wave = tid >> 6, l = tid & 63;
  const int c0 = 2*l, c1 = c0 + 1;

  __shared__ float Wt[NH][NH];  // Wt[k][c] = W_e2e[c][k]
  {
    const int c = tid & 127, half = tid >> 7;
    const float* src = W_e2e + c*NH + half*64;
    #pragma unroll
    for (int k0 = 0; k0 < 64; k0 += 4){
      float4 w = *(const float4*)(src + k0);
      Wt[half*64 + k0 + 0][c] = w.x;
      Wt[half*64 + k0 + 1][c] = w.y;
      Wt[half*64 + k0 + 2][c] = w.z;
      Wt[half*64 + k0 + 3][c] = w.w;
    }
  }
  __syncthreads();

  // per-lane channel constants (g_e/be_e/b_e2e kept for reference fidelity)
  const float* lo = lin_out + (size_t)(b*NN + j)*NH;
  const float bj0 = lo[c0] + b_e2e[c0];
  const float bj1 = lo[c1] + b_e2e[c1];
  const float ge0 = g_e[c0], ge1 = g_e[c1];
  const float bee0 = be_e[c0], bee1 = be_e[c1];

  const size_t ebase = ((size_t)b*NN)*NN*NH + (size_t)j*NH;
  const int* emcol = e_mask + (size_t)(b*NN)*NN + j;

  for (int t = 0; t < NN/4; ++t){
    const int i = t*4 + wave;   // each wave owns rows i ≡ wave (mod 4)

    // e row distributed across the wave: lane holds elements (2l, 2l+1)
    const float2 e2 = *(const float2*)(e + ebase + (size_t)i*NN*NH + c0);

    float a0 = 0.f, a1 = 0.f;
    #pragma unroll 8
    for (int k = 0; k < NH; k += 2){
      const float ex = __shfl(e2.x, k >> 1, 64);   // element k
      const float ey = __shfl(e2.y, k >> 1, 64);   // element k+1
      const float2 w0 = *(const float2*)&Wt[k][c0];
      const float2 w1 = *(const float2*)&Wt[k+1][c0];
      a0 += ex*w0.x + ey*w1.x;
      a1 += ex*w0.y + ey*w1.y;
    }

    const float2 li = *(const float2*)(lin_in + (size_t)(b*NN + i)*NH + c0);
    const float x0 = a0 + li.x + bj0;
    const float x1 = a1 + li.y + bj1;

    // LN over 128 channels = 64 lanes x 2
    float s = x0 + x1, s2 = x0*x0 + x1*x1;
    #pragma unroll
    for (int m = 1; m <= 32; m <<= 1){
      s  += __shfl_xor(s,  m, 64);
      s2 += __shfl_xor(s2, m, 64);
    }
    const float mu  = s * (1.f/NH);
    const float var = s2 * (1.f/NH) - mu*mu;
    const float rs  = rsqrtf(var + LN_EPS);

    float h0 = elu1((x0 - mu)*rs*ge0 + bee0);
    float h1 = elu1((x1 - mu)*rs*ge1 + bee1);
    const int zf = (i == j) || emcol[(size_t)i*NN];
    h0 = zf ? 0.f : h0;
    h1 = zf ? 0.f : h1;
    float2 hh; hh.x = h0; hh.y = h1;
    *(float2*)(out_e + ebase + (size_t)i*NN*NH + c0) = hh;
  }
}

// Kernel B (validated round 7): out_v from stored e_out.
__global__ __launch_bounds__(128) void vnew_from_eout_kernel(
    const float* __restrict__ v,
    const int* __restrict__ v_mask,
    const float* __restrict__ g_v, const float* __restrict__ be_v,
    const float* __restrict__ out_e,
    float* __restrict__ out_v)
{
  const int blk = blockIdx.x;  // b*NN + j
  const int b = blk >> 8, j = blk & (NN-1);
  const int c = threadIdx.x;   // 0..127
  const size_t ebase = ((size_t)b*NN)*NN*NH + (size_t)j*NH;

  float a = 0.f;
  for (int i = 0; i < NN; ++i)
    a += out_e[ebase + (size_t)i*NN*NH + c];

  __shared__ float red[4];
  float s = a, s2 = a*a;
  #pragma unroll
  for (int m = 1; m <= 32; m <<= 1){
    s  += __shfl_xor(s,  m, 64);
    s2 += __shfl_xor(s2, m, 64);
  }
  const int w = c >> 6;
  if ((c & 63) == 0){ red[w*2] = s; red[w*2+1] = s2; }
  __syncthreads();
  s  = red[0] + red[2];
  s2 = red[1] + red[3];

  const float mu  = s * (1.f/NH);
  const float var = s2 * (1.f/NH) - mu*mu;
  const float rs  = rsqrtf(var + LN_EPS);
  const float h   = elu1((a - mu)*rs*g_v[c] + be_v[c]);
  const int vm = v_mask[b*NN + j];
  const float vv = vm ? 0.f : v[(size_t)(b*NN + j)*NH + c];
  out_v[(size_t)(b*NN + j)*NH + c] = vv + h;
}

extern "C" void kernel_launch(void* const* d_in, const int* in_sizes, int n_in,
                              void* d_out, int out_size, void* d_ws, size_t ws_size,
                              hipStream_t stream)
{
  const float* v      = (const float*)d_in[0];
  const float* e      = (const float*)d_in[1];
  const int*   v_mask = (const int*)d_in[2];
  const int*   e_mask = (const int*)d_in[3];
  const float* W_in   = (const float*)d_in[4];
  const float* b_in   = (const float*)d_in[5];
  const float* W_out  = (const float*)d_in[6];
  const float* b_out  = (const float*)d_in[7];
  const float* W_e2e  = (const float*)d_in[8];
  const float* b_e2e  = (const float*)d_in[9];
  const float* g_e    = (const float*)d_in[10];
  const float* be_e   = (const float*)d_in[11];
  const float* g_v    = (const float*)d_in[12];
  const float* be_v   = (const float*)d_in[13];

  float* lin_in  = (float*)d_ws;                 // [NB*NN, NH]
  float* lin_out = lin_in + NB*NN*NH;            // [NB*NN, NH]
  float* out_v = (float*)d_out;                  // [NB,NN,NH]
  float* out_e = out_v + (size_t)NB*NN*NH;       // [NB,NN,NN,NH]

  lin_vw_kernel<<<NB*NN, NH, 0, stream>>>(v, W_in, b_in, W_out, b_out,
                                          lin_in, lin_out);
  nri_eout_fp32_kernel<<<NB*NN, 256, 0, stream>>>(e, e_mask,
                                                  W_e2e, b_e2e, g_e, be_e,
                                                  lin_in, lin_out, out_e);
  vnew_from_eout_kernel<<<NB*NN, 128, 0, stream>>>(v, v_mask, g_v, be_v,
                                                   out_e, out_v);
}

// Round 9
// 252.543 us; speedup vs baseline: 2.6777x; 2.6777x over previous
//
#include <hip/hip_runtime.h>

#define NB 4
#define NN 256
#define NH 128
#define LN_EPS 1e-5f

__device__ __forceinline__ float elu1(float x){
  return x > 0.f ? x : (__expf(x) - 1.f);
}

// K0: lin_in[b,i,:] = v@W_in.T + b_in ; lin_out[b,i,:] = v@W_out.T + b_out (fp32 exact)
__global__ __launch_bounds__(128) void lin_vw_kernel(
    const float* __restrict__ v,
    const float* __restrict__ W_in, const float* __restrict__ b_in,
    const float* __restrict__ W_out, const float* __restrict__ b_out,
    float* __restrict__ lin_in, float* __restrict__ lin_out)
{
  const int row = blockIdx.x;    // b*NN + i
  const int t = threadIdx.x;     // output col
  __shared__ float vs[NH];
  vs[t] = v[(size_t)row*NH + t];
  __syncthreads();
  const float4* wi = (const float4*)(W_in + t*NH);
  const float4* wo = (const float4*)(W_out + t*NH);
  const float4* vv = (const float4*)vs;
  float ai = b_in[t], ao = b_out[t];
  #pragma unroll
  for (int k = 0; k < NH/4; ++k){
    float4 x = vv[k];
    float4 a = wi[k], bq = wo[k];
    ai += x.x*a.x + x.y*a.y + x.z*a.z + x.w*a.w;
    ao += x.x*bq.x + x.y*bq.y + x.z*bq.z + x.w*bq.w;
  }
  lin_in[(size_t)row*NH + t]  = ai;
  lin_out[(size_t)row*NH + t] = ao;
}

// A'': register-tiled fp32 GEMM. One block per (b,j); thread (it,ic) computes
// 8 rows x 4 cols. W^T in LDS (b128 conflict-free); e read from global with
// 32-lane same-address broadcast (L1-served). 128 FMA per 12 memory ops.
__global__ __launch_bounds__(256) void nri_eout_tiled_kernel(
    const float* __restrict__ e,
    const int* __restrict__ e_mask,
    const float* __restrict__ W_e2e, const float* __restrict__ b_e2e,
    const float* __restrict__ g_e,   const float* __restrict__ be_e,
    const float* __restrict__ lin_in, const float* __restrict__ lin_out,
    float* __restrict__ out_e)
{
  const int blk = blockIdx.x, b = blk >> 8, j = blk & (NN-1);
  const int tid = threadIdx.x;
  const int it  = tid >> 5;      // 0..7 : row group
  const int ic  = tid & 31;      // cols 4ic .. 4ic+3
  const int c0  = 4*ic;

  __shared__ float Wt[NH][NH];   // Wt[k][c] = W_e2e[c][k]
  {
    const int c = tid >> 1, half = tid & 1;
    const float* src = W_e2e + c*NH + half*64;
    #pragma unroll
    for (int kk = 0; kk < 64; kk += 4){
      float4 w = *(const float4*)(src + kk);
      Wt[half*64 + kk + 0][c] = w.x;
      Wt[half*64 + kk + 1][c] = w.y;
      Wt[half*64 + kk + 2][c] = w.z;
      Wt[half*64 + kk + 3][c] = w.w;
    }
  }

  // per-thread column constants: lin_out[j,c] + b_e2e[c]; g_e, be_e
  float bj[4], gc[4], bec[4];
  {
    const float* lo = lin_out + (size_t)(b*NN + j)*NH + c0;
    #pragma unroll
    for (int cc = 0; cc < 4; ++cc){
      bj[cc]  = lo[cc] + b_e2e[c0+cc];
      gc[cc]  = g_e[c0+cc];
      bec[cc] = be_e[c0+cc];
    }
  }
  __syncthreads();

  const size_t ebase   = ((size_t)b*NN)*NN*NH + (size_t)j*NH;
  const size_t estride = (size_t)NN*NH;
  const int*   emcol   = e_mask + (size_t)(b*NN)*NN + j;

  for (int i0 = 0; i0 < NN; i0 += 64){
    const int ibase = i0 + it*8;

    const float* ep[8];
    #pragma unroll
    for (int rr = 0; rr < 8; ++rr)
      ep[rr] = e + ebase + (size_t)(ibase + rr)*estride;

    float acc[8][4];
    #pragma unroll
    for (int rr = 0; rr < 8; ++rr)
      #pragma unroll
      for (int cc = 0; cc < 4; ++cc) acc[rr][cc] = 0.f;

    for (int k = 0; k < NH; k += 4){
      const float4 w0 = *(const float4*)&Wt[k+0][c0];
      const float4 w1 = *(const float4*)&Wt[k+1][c0];
      const float4 w2 = *(const float4*)&Wt[k+2][c0];
      const float4 w3 = *(const float4*)&Wt[k+3][c0];
      #pragma unroll
      for (int rr = 0; rr < 8; ++rr){
        const float4 ev = *(const float4*)(ep[rr] + k);
        acc[rr][0] += ev.x*w0.x + ev.y*w1.x + ev.z*w2.x + ev.w*w3.x;
        acc[rr][1] += ev.x*w0.y + ev.y*w1.y + ev.z*w2.y + ev.w*w3.y;
        acc[rr][2] += ev.x*w0.z + ev.y*w1.z + ev.z*w2.z + ev.w*w3.z;
        acc[rr][3] += ev.x*w0.w + ev.y*w1.w + ev.z*w2.w + ev.w*w3.w;
      }
    }

    // epilogue: +lin_in +bias -> LN -> ELU -> mask -> store
    #pragma unroll
    for (int rr = 0; rr < 8; ++rr){
      const int i = ibase + rr;
      const float4 li = *(const float4*)(lin_in + (size_t)(b*NN + i)*NH + c0);
      float x0 = acc[rr][0] + li.x + bj[0];
      float x1 = acc[rr][1] + li.y + bj[1];
      float x2 = acc[rr][2] + li.z + bj[2];
      float x3 = acc[rr][3] + li.w + bj[3];

      // LN over 128 = 4 in-thread x 32 ic-lanes (same-it group = lanes 0..31 / 32..63)
      float s  = x0 + x1 + x2 + x3;
      float s2 = x0*x0 + x1*x1 + x2*x2 + x3*x3;
      #pragma unroll
      for (int m = 1; m <= 16; m <<= 1){
        s  += __shfl_xor(s,  m, 64);
        s2 += __shfl_xor(s2, m, 64);
      }
      const float mu  = s * (1.f/NH);
      const float var = s2 * (1.f/NH) - mu*mu;
      const float rs  = rsqrtf(var + LN_EPS);

      const int zf = (i == j) || emcol[(size_t)i*NN];
      float4 hh;
      hh.x = zf ? 0.f : elu1((x0 - mu)*rs*gc[0] + bec[0]);
      hh.y = zf ? 0.f : elu1((x1 - mu)*rs*gc[1] + bec[1]);
      hh.z = zf ? 0.f : elu1((x2 - mu)*rs*gc[2] + bec[2]);
      hh.w = zf ? 0.f : elu1((x3 - mu)*rs*gc[3] + bec[3]);
      *(float4*)(out_e + ebase + (size_t)i*estride + c0) = hh;
    }
  }
}

// Kernel B (validated round 7/8): out_v from stored e_out. i-loop unrolled 8x.
__global__ __launch_bounds__(128) void vnew_from_eout_kernel(
    const float* __restrict__ v,
    const int* __restrict__ v_mask,
    const float* __restrict__ g_v, const float* __restrict__ be_v,
    const float* __restrict__ out_e,
    float* __restrict__ out_v)
{
  const int blk = blockIdx.x;  // b*NN + j
  const int b = blk >> 8, j = blk & (NN-1);
  const int c = threadIdx.x;   // 0..127
  const size_t ebase = ((size_t)b*NN)*NN*NH + (size_t)j*NH;

  float a = 0.f;
  for (int i = 0; i < NN; i += 8){
    float p0 = out_e[ebase + (size_t)(i+0)*NN*NH + c];
    float p1 = out_e[ebase + (size_t)(i+1)*NN*NH + c];
    float p2 = out_e[ebase + (size_t)(i+2)*NN*NH + c];
    float p3 = out_e[ebase + (size_t)(i+3)*NN*NH + c];
    float p4 = out_e[ebase + (size_t)(i+4)*NN*NH + c];
    float p5 = out_e[ebase + (size_t)(i+5)*NN*NH + c];
    float p6 = out_e[ebase + (size_t)(i+6)*NN*NH + c];
    float p7 = out_e[ebase + (size_t)(i+7)*NN*NH + c];
    a += ((p0 + p1) + (p2 + p3)) + ((p4 + p5) + (p6 + p7));
  }

  __shared__ float red[4];
  float s = a, s2 = a*a;
  #pragma unroll
  for (int m = 1; m <= 32; m <<= 1){
    s  += __shfl_xor(s,  m, 64);
    s2 += __shfl_xor(s2, m, 64);
  }
  const int w = c >> 6;
  if ((c & 63) == 0){ red[w*2] = s; red[w*2+1] = s2; }
  __syncthreads();
  s  = red[0] + red[2];
  s2 = red[1] + red[3];

  const float mu  = s * (1.f/NH);
  const float var = s2 * (1.f/NH) - mu*mu;
  const float rs  = rsqrtf(var + LN_EPS);
  const float h   = elu1((a - mu)*rs*g_v[c] + be_v[c]);
  const int vm = v_mask[b*NN + j];
  const float vv = vm ? 0.f : v[(size_t)(b*NN + j)*NH + c];
  out_v[(size_t)(b*NN + j)*NH + c] = vv + h;
}

extern "C" void kernel_launch(void* const* d_in, const int* in_sizes, int n_in,
                              void* d_out, int out_size, void* d_ws, size_t ws_size,
                              hipStream_t stream)
{
  const float* v      = (const float*)d_in[0];
  const float* e      = (const float*)d_in[1];
  const int*   v_mask = (const int*)d_in[2];
  const int*   e_mask = (const int*)d_in[3];
  const float* W_in   = (const float*)d_in[4];
  const float* b_in   = (const float*)d_in[5];
  const float* W_out  = (const float*)d_in[6];
  const float* b_out  = (const float*)d_in[7];
  const float* W_e2e  = (const float*)d_in[8];
  const float* b_e2e  = (const float*)d_in[9];
  const float* g_e    = (const float*)d_in[10];
  const float* be_e   = (const float*)d_in[11];
  const float* g_v    = (const float*)d_in[12];
  const float* be_v   = (const float*)d_in[13];

  float* lin_in  = (float*)d_ws;                 // [NB*NN, NH]
  float* lin_out = lin_in + NB*NN*NH;            // [NB*NN, NH]
  float* out_v = (float*)d_out;                  // [NB,NN,NH]
  float* out_e = out_v + (size_t)NB*NN*NH;       // [NB,NN,NN,NH]

  lin_vw_kernel<<<NB*NN, NH, 0, stream>>>(v, W_in, b_in, W_out, b_out,
                                          lin_in, lin_out);
  nri_eout_tiled_kernel<<<NB*NN, 256, 0, stream>>>(e, e_mask,
                                                   W_e2e, b_e2e, g_e, be_e,
                                                   lin_in, lin_out, out_e);
  vnew_from_eout_kernel<<<NB*NN, 128, 0, stream>>>(v, v_mask, g_v, be_v,
                                                   out_e, out_v);
}